// Round 4
// baseline (203.666 us; speedup 1.0000x reference)
//
#include <hip/hip_runtime.h>

#define BINS 128
#define FEAT 64
#define SEG (BINS * FEAT)     // 8192 counters per batch histogram
#define B_DIM 32
#define S_DIM 16384
#define CHUNKS 16             // S-chunks per batch -> 512 blocks (2 per CU)
#define THREADS 512           // 8 waves
#define UNROLL 8
#define ROWS_PER_BLOCK (S_DIM / CHUNKS)                // 1024
#define ROWS_PER_WAVE  (ROWS_PER_BLOCK / (THREADS/64)) // 128

// Single fused kernel. grid = (CHUNKS, B_DIM), block = THREADS.
// Phase 1: LDS uint histogram over this block's S-chunk (ds_add_u32,
//          addr = bin*64+lane -> distinct per lane, free 2-way bank alias).
// Phase 2: merge straight into d_out, applying weights inline:
//          atomicAdd(&out[b][i], (float)count * w[i])  -- HW f32 atomic,
//          memory-side coherent, exact because every partial sum is an
//          integer < 2^24 (counts <= 16384, weights == 1.0f).
__global__ __launch_bounds__(THREADS, 4)   // 2 blocks/CU (16 waves), LDS 2x32K
void hist_fused_kernel(const float* __restrict__ x,
                       const float* __restrict__ w,
                       float* __restrict__ out) {
    __shared__ unsigned hist[SEG];
    for (int i = threadIdx.x; i < SEG; i += THREADS) hist[i] = 0u;
    __syncthreads();

    const int c    = blockIdx.x;
    const int b    = blockIdx.y;
    const int lane = threadIdx.x & 63;
    const int wave = threadIdx.x >> 6;               // 0..7

    const float* xb = x + ((size_t)b * S_DIM
                           + (size_t)c * ROWS_PER_BLOCK
                           + wave * ROWS_PER_WAVE) * FEAT;

    for (int it = 0; it < ROWS_PER_WAVE; it += UNROLL) {
        float v[UNROLL];
        #pragma unroll
        for (int u = 0; u < UNROLL; ++u)
            v[u] = xb[(it + u) * FEAT + lane];       // coalesced 256B/wave/load
        #pragma unroll
        for (int u = 0; u < UNROLL; ++u) {
            int bin = (int)(v[u] * 128.0f);          // exact: x*2^7, trunc like ref
            bin = bin < 0 ? 0 : (bin > 127 ? 127 : bin);
            atomicAdd(&hist[(bin << 6) + lane], 1u); // ds_add_u32
        }
    }
    __syncthreads();

    // Merge with weights fused: 8192 elems / 512 threads = 16 atomics/thread.
    float* gout = out + (size_t)b * SEG;             // out[b][bin][f] == hist layout
    for (int i = threadIdx.x; i < SEG; i += THREADS) {
        unsigned cnt = hist[i];
        if (cnt) atomicAdd(&gout[i], (float)cnt * w[i]);  // global_atomic_add_f32
    }
}

extern "C" void kernel_launch(void* const* d_in, const int* in_sizes, int n_in,
                              void* d_out, int out_size, void* d_ws, size_t ws_size,
                              hipStream_t stream) {
    const float* x = (const float*)d_in[0];
    const float* w = (const float*)d_in[1];
    float* out = (float*)d_out;

    // d_out is poisoned 0xAA before every call -> zero it (1 MiB, ~0.3 us).
    hipMemsetAsync(d_out, 0, (size_t)out_size * sizeof(float), stream);

    dim3 grid(CHUNKS, B_DIM);
    hist_fused_kernel<<<grid, THREADS, 0, stream>>>(x, w, out);
}